// Round 3
// baseline (494.488 us; speedup 1.0000x reference)
//
#include <hip/hip_runtime.h>

// int4-dequant GEMM: y[m,n] = sum_k x[m,k] * scale[n, k/128] * (q[n,k] - 8)
// Harness upcasts the reference's fp16 tensors to FLOAT32 device buffers
// (evidence: NaN from reading f32 mantissa halves as bf16 in rounds 1-2;
//  threshold 1.93 = 8 * 2^-11 * max|ref| is fp16-eps-scaled; out "else float*").
// x: (512, 4096) float32
// weight_packed: (11008, 2048) int32, low byte = 2 nibbles (low=even k, high=odd k)
// scales: (11008, 32) float32
// out: (512, 11008) float32
//
// In-kernel: convert x -> bf16 (RNE) while staging, dequant int4 -> bf16,
// mfma_f32_16x16x32_bf16, f32 accumulate, f32 store.

typedef __attribute__((ext_vector_type(8))) short short8;   // MFMA A/B frag: 8 bf16 bits
typedef __attribute__((ext_vector_type(4))) float f32x4;    // MFMA C/D frag / float4 load
typedef __attribute__((ext_vector_type(4))) int   i32x4;    // 16B load/store unit
typedef __attribute__((ext_vector_type(2))) int   i32x2;    // 8B store unit

#define M_DIM 512
#define N_DIM 11008
#define K_DIM 4096
#define BM 128
#define BN 128
#define BK 64
#define PAD 8       // +8 shorts = +16B: rows stay 16B-aligned, breaks power-of-2 bank stride
#define THREADS 256

__device__ __forceinline__ unsigned int f2bf(float f) {   // f32 -> bf16 bits, RNE, finite-only
    union { float f; unsigned int u; } c; c.f = f;
    return (c.u + 0x7FFFu + ((c.u >> 16) & 1u)) >> 16;
}

__global__ __launch_bounds__(THREADS, 2)
void dq_gemm(const float* __restrict__ x,
             const int* __restrict__ wp,
             const float* __restrict__ scales,
             float* __restrict__ out)
{
    __shared__ __align__(16) unsigned short sA[BM][BK + PAD];  // x tile (bf16 bits) [m][k]
    __shared__ __align__(16) unsigned short sB[BN][BK + PAD];  // dequant w tile     [n][k]

    const int t  = threadIdx.x;
    const int m0 = blockIdx.x * BM;   // m fastest => same-n blocks co-run (L2/L3 weight reuse)
    const int n0 = blockIdx.y * BN;

    const int wave = t >> 6;
    const int lane = t & 63;
    const int wm = (wave & 1) * 64;   // wave m-offset
    const int wn = (wave >> 1) * 64;  // wave n-offset
    const int lm = lane & 15;         // A/B frag: row = lane & 15
    const int lk = (lane >> 4) * 8;   // A/B frag: k = quad*8 + j

    f32x4 acc[4][4] = {};             // wave computes 64x64

    // B staging: 256 threads x 4 iters cover 128 rows x 64 k (16B packed per thread-iter)
    const int srow = t >> 3;          // 0..31, +32 per iter
    const int icB  = (t & 7) * 4;     // int32-col offset for w (4 ints = 8 k)

    const float* xg = x + (size_t)m0 * K_DIM;
    const int*   wg = wp + (size_t)n0 * (K_DIM / 2);

    for (int kb = 0; kb < K_DIM; kb += BK) {
        const int g = kb >> 7;        // quant group (128 k / group; BK tile never straddles)

        // ---- stage A: f32 tile -> bf16 LDS. 2048 float4 chunks, 8 per thread ----
        #pragma unroll
        for (int i = 0; i < 8; ++i) {
            int c   = i * 256 + t;
            int row = c >> 4;          // 16 float4 per 64-wide row
            int c4  = (c & 15) * 4;    // f32 col offset
            f32x4 v = *(const f32x4*)(xg + (size_t)row * K_DIM + kb + c4);
            i32x2 p;
            p[0] = (int)(f2bf(v[0]) | (f2bf(v[1]) << 16));
            p[1] = (int)(f2bf(v[2]) | (f2bf(v[3]) << 16));
            *(i32x2*)&sA[row][c4] = p;  // 8B store, aligned (row stride 144B, c4*2 % 8 == 0)
        }

        // ---- stage B: load packed nibbles, dequant to bf16 bits, 16B store ----
        #pragma unroll
        for (int i = 0; i < 4; ++i) {
            int row = srow + i * 32;
            i32x4 pv = *(const i32x4*)(wg + (size_t)row * (K_DIM / 2) + (kb >> 1) + icB);
            float s = scales[(size_t)(n0 + row) * (K_DIM / 128) + g];
            i32x4 res;
            #pragma unroll
            for (int e = 0; e < 4; ++e) {
                int q = pv[e];
                unsigned int lo = f2bf((float)((q & 15) - 8) * s);        // even k
                unsigned int hi = f2bf((float)(((q >> 4) & 15) - 8) * s); // odd k
                res[e] = (int)((hi << 16) | lo);
            }
            *(i32x4*)&sB[row][icB * 2] = res;
        }

        __syncthreads();

        // ---- compute: 2 k-steps of 32, 16 MFMA each ----
        #pragma unroll
        for (int ks = 0; ks < BK; ks += 32) {
            short8 a[4], b[4];
            #pragma unroll
            for (int i = 0; i < 4; ++i)
                a[i] = *(const short8*)&sA[wm + i * 16 + lm][ks + lk];
            #pragma unroll
            for (int j = 0; j < 4; ++j)
                b[j] = *(const short8*)&sB[wn + j * 16 + lm][ks + lk];
            #pragma unroll
            for (int i = 0; i < 4; ++i)
                #pragma unroll
                for (int j = 0; j < 4; ++j)
                    acc[i][j] = __builtin_amdgcn_mfma_f32_16x16x32_bf16(
                        a[i], b[j], acc[i][j], 0, 0, 0);
        }

        __syncthreads();
    }

    // ---- epilogue: C/D layout col(n)=lane&15, row(m)=quad*4+reg; f32 store ----
    #pragma unroll
    for (int i = 0; i < 4; ++i) {
        int mg = m0 + wm + i * 16 + (lane >> 4) * 4;
        #pragma unroll
        for (int j = 0; j < 4; ++j) {
            int ng = n0 + wn + j * 16 + lm;
            #pragma unroll
            for (int r = 0; r < 4; ++r)
                out[(size_t)(mg + r) * N_DIM + ng] = acc[i][j][r];
        }
    }
}

extern "C" void kernel_launch(void* const* d_in, const int* in_sizes, int n_in,
                              void* d_out, int out_size, void* d_ws, size_t ws_size,
                              hipStream_t stream) {
    const float* x      = (const float*)d_in[0];
    const int*   wpck   = (const int*)d_in[1];
    const float* scales = (const float*)d_in[2];
    float*       out    = (float*)d_out;

    dim3 grid(M_DIM / BM, N_DIM / BN);   // (4, 86) = 344 blocks
    dq_gemm<<<grid, dim3(THREADS), 0, stream>>>(x, wpck, scales, out);
}

// Round 4
// 295.703 us; speedup vs baseline: 1.6722x; 1.6722x over previous
//
#include <hip/hip_runtime.h>

// int4-dequant GEMM: y[m,n] = sum_k x[m,k] * scale[n, k/128] * (q[n,k] - 8)
// x: (512, 4096) f32 | weight_packed: (11008, 2048) int32 (2 nibbles/low byte) |
// scales: (11008, 32) f32 | out: (512, 11008) f32
//
// R4: occupancy rewrite. 344 blocks -> 1376 (64x64 tiles), plus x pre-converted
// to bf16 in d_ws once per launch (kills the x86-duplicated f32->bf16 VALU and
// halves A staging bytes). R3 was 16% occupancy, all pipes <15% => latency-bound.

typedef __attribute__((ext_vector_type(8))) short short8;   // MFMA A/B frag
typedef __attribute__((ext_vector_type(4))) float f32x4;
typedef __attribute__((ext_vector_type(4))) int   i32x4;
typedef __attribute__((ext_vector_type(2))) int   i32x2;

#define M_DIM 512
#define N_DIM 11008
#define K_DIM 4096
#define BM 64
#define BN 64
#define BK 64
#define PAD 8       // row stride 72 shorts = 144B: 2-way bank alias max (free)
#define THREADS 256

__device__ __forceinline__ unsigned int f2bf(float f) {   // f32 -> bf16 bits, RNE
    union { float f; unsigned int u; } c; c.f = f;
    return (c.u + 0x7FFFu + ((c.u >> 16) & 1u)) >> 16;
}

// ---- kernel 1: x f32 -> bf16 into workspace (512*4096 = 2.1M elems) ----
__global__ __launch_bounds__(THREADS)
void cvt_x(const float* __restrict__ x, unsigned short* __restrict__ xw)
{
    int idx = (blockIdx.x * THREADS + threadIdx.x) * 4;
    f32x4 v = *(const f32x4*)(x + idx);
    i32x2 p;
    p[0] = (int)(f2bf(v[0]) | (f2bf(v[1]) << 16));
    p[1] = (int)(f2bf(v[2]) | (f2bf(v[3]) << 16));
    *(i32x2*)(xw + idx) = p;
}

// ---- kernel 2: 64x64 tile GEMM, 4 waves of 32x32, grid (8,172)=1376 blocks ----
template<bool PRECVT>
__global__ __launch_bounds__(THREADS, 4)
void dq_gemm(const unsigned short* __restrict__ xw,  // bf16 bits (PRECVT)
             const float* __restrict__ xf,           // f32 fallback
             const int* __restrict__ wp,
             const float* __restrict__ scales,
             float* __restrict__ out)
{
    __shared__ __align__(16) unsigned short sA[BM][BK + PAD];
    __shared__ __align__(16) unsigned short sB[BN][BK + PAD];

    const int t  = threadIdx.x;
    const int m0 = blockIdx.x * BM;   // m fastest: 8 consecutive blocks share the n-tile
    const int n0 = blockIdx.y * BN;

    const int wave = t >> 6;
    const int lane = t & 63;
    const int wm = (wave & 1) * 32;
    const int wn = (wave >> 1) * 32;
    const int lm = lane & 15;         // A/B frag row
    const int lk = (lane >> 4) * 8;   // A/B frag k = quad*8

    f32x4 acc[2][2] = {};

    const int* wg = wp + (size_t)n0 * (K_DIM / 2);

    for (int kb = 0; kb < K_DIM; kb += BK) {
        const int g = kb >> 7;

        // ---- stage A: 64x64 bf16 = 512 16B chunks, 2/thread ----
        if (PRECVT) {
            #pragma unroll
            for (int i = 0; i < 2; ++i) {
                int c = i * 256 + t;
                int row = c >> 3, col = (c & 7) * 8;
                i32x4 v = *(const i32x4*)(xw + (size_t)(m0 + row) * K_DIM + kb + col);
                *(i32x4*)&sA[row][col] = v;
            }
        } else {
            #pragma unroll
            for (int i = 0; i < 4; ++i) {        // 1024 float4 chunks, 4/thread
                int c = i * 256 + t;
                int row = c >> 4, col = (c & 15) * 4;
                f32x4 v = *(const f32x4*)(xf + (size_t)(m0 + row) * K_DIM + kb + col);
                i32x2 p;
                p[0] = (int)(f2bf(v[0]) | (f2bf(v[1]) << 16));
                p[1] = (int)(f2bf(v[2]) | (f2bf(v[3]) << 16));
                *(i32x2*)&sA[row][col] = p;
            }
        }

        // ---- stage B: 64 rows x 32 ints = 512 16B chunks, 2/thread, dequant ----
        #pragma unroll
        for (int i = 0; i < 2; ++i) {
            int c = i * 256 + t;
            int row = c >> 3, ic = (c & 7) * 4;
            i32x4 pv = *(const i32x4*)(wg + (size_t)row * (K_DIM / 2) + (kb >> 1) + ic);
            float s = scales[(size_t)(n0 + row) * (K_DIM / 128) + g];
            i32x4 res;
            #pragma unroll
            for (int e = 0; e < 4; ++e) {
                int q = pv[e];
                unsigned int lo = f2bf((float)((q & 15) - 8) * s);        // even k
                unsigned int hi = f2bf((float)(((q >> 4) & 15) - 8) * s); // odd k
                res[e] = (int)((hi << 16) | lo);
            }
            *(i32x4*)&sB[row][ic * 2] = res;
        }

        __syncthreads();

        #pragma unroll
        for (int ks = 0; ks < BK; ks += 32) {
            short8 a[2], b[2];
            #pragma unroll
            for (int i = 0; i < 2; ++i)
                a[i] = *(const short8*)&sA[wm + i * 16 + lm][ks + lk];
            #pragma unroll
            for (int j = 0; j < 2; ++j)
                b[j] = *(const short8*)&sB[wn + j * 16 + lm][ks + lk];
            #pragma unroll
            for (int i = 0; i < 2; ++i)
                #pragma unroll
                for (int j = 0; j < 2; ++j)
                    acc[i][j] = __builtin_amdgcn_mfma_f32_16x16x32_bf16(
                        a[i], b[j], acc[i][j], 0, 0, 0);
        }

        __syncthreads();
    }

    // ---- epilogue: C/D col(n)=lane&15, row(m)=quad*4+reg ----
    #pragma unroll
    for (int i = 0; i < 2; ++i) {
        int mg = m0 + wm + i * 16 + (lane >> 4) * 4;
        #pragma unroll
        for (int j = 0; j < 2; ++j) {
            int ng = n0 + wn + j * 16 + lm;
            #pragma unroll
            for (int r = 0; r < 4; ++r)
                out[(size_t)(mg + r) * N_DIM + ng] = acc[i][j][r];
        }
    }
}

extern "C" void kernel_launch(void* const* d_in, const int* in_sizes, int n_in,
                              void* d_out, int out_size, void* d_ws, size_t ws_size,
                              hipStream_t stream) {
    const float* x      = (const float*)d_in[0];
    const int*   wpck   = (const int*)d_in[1];
    const float* scales = (const float*)d_in[2];
    float*       out    = (float*)d_out;

    dim3 grid(M_DIM / BM, N_DIM / BN);   // (8, 172) = 1376 blocks
    const size_t xw_bytes = (size_t)M_DIM * K_DIM * sizeof(unsigned short);  // 4 MB

    if (ws_size >= xw_bytes) {
        unsigned short* xw = (unsigned short*)d_ws;
        cvt_x<<<(M_DIM * K_DIM) / (THREADS * 4), THREADS, 0, stream>>>(x, xw);
        dq_gemm<true><<<grid, dim3(THREADS), 0, stream>>>(xw, x, wpck, scales, out);
    } else {
        dq_gemm<false><<<grid, dim3(THREADS), 0, stream>>>(nullptr, x, wpck, scales, out);
    }
}

// Round 5
// 252.235 us; speedup vs baseline: 1.9604x; 1.1723x over previous
//
#include <hip/hip_runtime.h>

// int4-dequant GEMM: y[m,n] = sum_k x[m,k] * scale[n, k/128] * (q[n,k] - 8)
// x: (512,4096) f32 | weight_packed: (11008,2048) int32, value<256 = 2 nibbles |
// scales: (11008,32) f32 | out: (512,11008) f32
//
// R5: BM=256 (weight-dequant dup 8->2) + split-K x4 for occupancy (688 blocks)
// + 32x32x16 MFMA with 128x64 wave tiles (LDS frag reuse 4x/2x) + XCD swizzle
// pairing the two m-blocks of each (n,ks) on one XCD + f32 atomic epilogue.

typedef __attribute__((ext_vector_type(8)))  short short8;   // 32x32x16 A/B frag (8 bf16)
typedef __attribute__((ext_vector_type(16))) float f32x16;   // 32x32x16 C/D frag
typedef __attribute__((ext_vector_type(4)))  float f32x4;
typedef __attribute__((ext_vector_type(4)))  int   i32x4;
typedef __attribute__((ext_vector_type(2)))  int   i32x2;

#define M_DIM 512
#define N_DIM 11008
#define K_DIM 4096
#define BM 256
#define BN 128
#define BK 64
#define KSPLIT 4
#define PAD 8
#define THREADS 256

__device__ __forceinline__ unsigned int fbits(float f) {
    union { float f; unsigned int u; } c; c.f = f; return c.u;
}
__device__ __forceinline__ unsigned int f2bf(float f) {   // RNE, finite-only
    unsigned int u = fbits(f);
    return (u + 0x7FFFu + ((u >> 16) & 1u)) >> 16;
}
__device__ __forceinline__ int pack_bf16(float flo, float fhi) {  // RNE both halves
    unsigned int ul = fbits(flo), uh = fbits(fhi);
    unsigned int lo = (ul + 0x7FFFu + ((ul >> 16) & 1u)) >> 16;
    unsigned int hi = (uh + 0x7FFFu + ((uh >> 16) & 1u)) & 0xFFFF0000u;
    return (int)(hi | lo);
}

// ---- x f32 -> bf16 workspace (2048 blocks) ----
__global__ __launch_bounds__(THREADS)
void cvt_x(const float* __restrict__ x, unsigned short* __restrict__ xw)
{
    int idx = (blockIdx.x * THREADS + threadIdx.x) * 4;
    f32x4 v = *(const f32x4*)(x + idx);
    i32x2 p;
    p[0] = (int)(f2bf(v[0]) | (f2bf(v[1]) << 16));
    p[1] = (int)(f2bf(v[2]) | (f2bf(v[3]) << 16));
    *(i32x2*)(xw + idx) = p;
}

// ---- zero the output (atomic accumulation needs it; harness poisons 0xAA) ----
__global__ __launch_bounds__(THREADS)
void zero_out(float* __restrict__ out)
{
    int idx = (blockIdx.x * THREADS + threadIdx.x) * 4;
    *(f32x4*)(out + idx) = (f32x4){0.f, 0.f, 0.f, 0.f};
}

// ---- main GEMM: 256x128 tile, K/4 per block, 4 waves of 128x64 ----
template<bool PRECVT>
__global__ __launch_bounds__(THREADS, 2)
void dq_gemm(const unsigned short* __restrict__ xw,
             const float* __restrict__ xf,
             const int* __restrict__ wp,
             const float* __restrict__ scales,
             float* __restrict__ out)
{
    __shared__ __align__(16) unsigned short sA[BM][BK + PAD];  // 36.9 KB
    __shared__ __align__(16) unsigned short sB[BN][BK + PAD];  // 18.4 KB

    const int t  = threadIdx.x;
    const int bx = blockIdx.x;
    // swizzle: ids differing by 8 (same XCD under %8 round-robin) are the two
    // m-blocks of one (n,ks) -> weight tile fetched once per XCD L2.
    const int m_idx = (bx >> 3) & 1;
    const int rest  = (bx & 7) | ((bx >> 4) << 3);   // [0, 344)
    const int ksp   = rest & 3;
    const int nb    = rest >> 2;                     // [0, 86)
    const int m0 = m_idx * BM;
    const int n0 = nb * BN;
    const int k0 = ksp * (K_DIM / KSPLIT);

    const int wave = t >> 6;
    const int lane = t & 63;
    const int wm = (wave & 1) * 128;   // wave m-offset (2 m-waves)
    const int wn = (wave >> 1) * 64;   // wave n-offset (2 n-waves)
    const int lr = lane & 31;          // frag row: lane & 31
    const int lk = (lane >> 5) * 8;    // frag k: (lane>>5)*8 + j

    f32x16 acc[4][2] = {};             // wave tile 128x64 = 4x2 of 32x32

    for (int kk = 0; kk < (K_DIM / KSPLIT) / BK; ++kk) {
        const int kb = k0 + kk * BK;
        const int g  = kb >> 7;        // quant group (BK=64 never straddles 128)

        // ---- stage A: 256x64 bf16 = 2048 16B chunks, 8/thread ----
        if (PRECVT) {
            #pragma unroll
            for (int i = 0; i < 8; ++i) {
                int c = i * 256 + t;
                int row = c >> 3, col = (c & 7) * 8;
                *(i32x4*)&sA[row][col] =
                    *(const i32x4*)(xw + (size_t)(m0 + row) * K_DIM + kb + col);
            }
        } else {
            #pragma unroll
            for (int i = 0; i < 16; ++i) {
                int c = i * 256 + t;
                int row = c >> 4, col = (c & 15) * 4;
                f32x4 v = *(const f32x4*)(xf + (size_t)(m0 + row) * K_DIM + kb + col);
                i32x2 p;
                p[0] = (int)(f2bf(v[0]) | (f2bf(v[1]) << 16));
                p[1] = (int)(f2bf(v[2]) | (f2bf(v[3]) << 16));
                *(i32x2*)&sA[row][col] = p;
            }
        }

        // ---- stage B: 128 rows x 32 ints, dequant+scale -> bf16, 4 chunks/thread ----
        #pragma unroll
        for (int i = 0; i < 4; ++i) {
            int c = i * 256 + t;
            int row = c >> 3, ic = (c & 7) * 4;
            i32x4 pv = *(const i32x4*)(wp + (size_t)(n0 + row) * (K_DIM / 2) + (kb >> 1) + ic);
            float s  = scales[(size_t)(n0 + row) * (K_DIM / 128) + g];
            float s8 = s * 8.0f;
            i32x4 res;
            #pragma unroll
            for (int e = 0; e < 4; ++e) {
                int b = pv[e];                                  // value < 256
                float flo = (float)(b & 15) * s - s8;           // (q_lo - 8) * s
                float fhi = (float)((b >> 4) & 15) * s - s8;    // (q_hi - 8) * s
                res[e] = pack_bf16(flo, fhi);
            }
            *(i32x4*)&sB[row][ic * 2] = res;
        }

        __syncthreads();

        // ---- compute: 4 k-steps of 16, 8 MFMA(32x32x16) each ----
        #pragma unroll
        for (int ks = 0; ks < BK; ks += 16) {
            short8 a[4], b[2];
            #pragma unroll
            for (int i = 0; i < 4; ++i)
                a[i] = *(const short8*)&sA[wm + i * 32 + lr][ks + lk];
            #pragma unroll
            for (int j = 0; j < 2; ++j)
                b[j] = *(const short8*)&sB[wn + j * 32 + lr][ks + lk];
            #pragma unroll
            for (int i = 0; i < 4; ++i)
                #pragma unroll
                for (int j = 0; j < 2; ++j)
                    acc[i][j] = __builtin_amdgcn_mfma_f32_32x32x16_bf16(
                        a[i], b[j], acc[i][j], 0, 0, 0);
        }

        __syncthreads();
    }

    // ---- epilogue: 32x32 C/D layout col=lane&31, row=(r&3)+8*(r>>2)+4*(lane>>5) ----
    const int rbase = (lane >> 5) * 4;
    #pragma unroll
    for (int i = 0; i < 4; ++i) {
        int mg = m0 + wm + i * 32 + rbase;
        #pragma unroll
        for (int j = 0; j < 2; ++j) {
            int ng = n0 + wn + j * 32 + lr;
            #pragma unroll
            for (int r = 0; r < 16; ++r) {
                int m = mg + (r & 3) + 8 * (r >> 2);
                unsafeAtomicAdd(&out[(size_t)m * N_DIM + ng], acc[i][j][r]);
            }
        }
    }
}

extern "C" void kernel_launch(void* const* d_in, const int* in_sizes, int n_in,
                              void* d_out, int out_size, void* d_ws, size_t ws_size,
                              hipStream_t stream) {
    const float* x      = (const float*)d_in[0];
    const int*   wpck   = (const int*)d_in[1];
    const float* scales = (const float*)d_in[2];
    float*       out    = (float*)d_out;

    zero_out<<<(M_DIM * N_DIM) / (THREADS * 4), THREADS, 0, stream>>>(out);

    const int grid = (M_DIM / BM) * (N_DIM / BN) * KSPLIT;   // 2*86*4 = 688
    const size_t xw_bytes = (size_t)M_DIM * K_DIM * sizeof(unsigned short);  // 4 MB

    if (ws_size >= xw_bytes) {
        unsigned short* xw = (unsigned short*)d_ws;
        cvt_x<<<(M_DIM * K_DIM) / (THREADS * 4), THREADS, 0, stream>>>(x, xw);
        dq_gemm<true><<<grid, dim3(THREADS), 0, stream>>>(xw, x, wpck, scales, out);
    } else {
        dq_gemm<false><<<grid, dim3(THREADS), 0, stream>>>(nullptr, x, wpck, scales, out);
    }
}